// Round 1
// 2528.952 us; speedup vs baseline: 1.1259x; 1.1259x over previous
//
#include <hip/hip_runtime.h>
#include <cfloat>
#include <climits>

#define T_TOKENS 65536
#define K_EMB 4096
#define D_DIM 256
#define QOFF ((size_t)T_TOKENS * D_DIM)   // 16777216
#define BT 128        // tokens per block
#define KHALF 2048    // codes per k-split half
#define NTILE 16      // k-tiles per half (128 codes each)
#define NCHUNK (NTILE * 8)   // 128 d-chunks of 32 floats

// fp32 multiply, contraction into later add blocked (numpy rounds the square first)
__device__ __forceinline__ float fmul_nc(float a, float b) {
    float c = a * b;
    asm volatile("" : "+v"(c));
    return c;
}

__device__ __forceinline__ double wave_sum_d(double v) {
#pragma unroll
    for (int o = 32; o >= 1; o >>= 1) v += __shfl_down(v, o, 64);
    return v;
}

// async global->LDS DMA, 16B per lane; lds base must be wave-uniform.
__device__ __forceinline__ void glds16(const float* g, float* l) {
    __builtin_amdgcn_global_load_lds((const __attribute__((address_space(1))) void*)g,
                                     (__attribute__((address_space(3))) void*)l, 16, 0, 0);
}

// A32[t] = np.float32 pairwise sum of z[t]**2 (two 128-halves, 8 strided
// accumulators, ((r0+r1)+(r2+r3))+((r4+r5)+(r6+r7)), then h0+h1). Validated r4.
__global__ __launch_bounds__(256)
void a32_kernel(const float* __restrict__ z, float* __restrict__ a32) {
    __shared__ float lds[64][257];
    const int tid = threadIdx.x;
    const int t0 = blockIdx.x * 256;
    for (int sub = 0; sub < 4; sub++) {
        const int tb = t0 + sub * 64;
        __syncthreads();
        for (int idx = tid; idx < 64 * 256; idx += 256) {
            const int r = idx >> 8, c = idx & 255;
            lds[r][c] = z[(size_t)(tb + r) * D_DIM + c];
        }
        __syncthreads();
        if (tid < 64) {
            const float* row = lds[tid];
            float S[2];
            for (int h = 0; h < 2; h++) {
                const float* p = row + h * 128;
                float r[8];
#pragma unroll
                for (int j = 0; j < 8; j++) r[j] = fmul_nc(p[j], p[j]);
                for (int m = 1; m < 16; m++) {
#pragma unroll
                    for (int j = 0; j < 8; j++) r[j] += fmul_nc(p[8 * m + j], p[8 * m + j]);
                }
                S[h] = ((r[0] + r[1]) + (r[2] + r[3])) + ((r[4] + r[5]) + (r[6] + r[7]));
            }
            a32[tb + tid] = S[0] + S[1];
        }
    }
}

// C32[k] = fp32(||e_k||^2) — the +C add is annihilated by fp32 rounding anyway.
__global__ void c32_kernel(const float* __restrict__ emb, float* __restrict__ c32) {
    const int k = blockIdx.x;
    const double v = (double)emb[(size_t)k * D_DIM + threadIdx.x];
    double s = wave_sum_d(v * v);
    __shared__ double wsm[4];
    const int lane = threadIdx.x & 63, w = threadIdx.x >> 6;
    if (lane == 0) wsm[w] = s;
    __syncthreads();
    if (threadIdx.x == 0) c32[k] = (float)(wsm[0] + wsm[1] + wsm[2] + wsm[3]);
}

// Argmin GEMM, v2: global_load_lds direct-to-LDS staging, double-buffered,
// one barrier per chunk, XOR-swizzled layout (source-side swizzle + read-side
// swizzle, same involution: slot ^= row&7). Per-(t,k) fp32 fmaf chain is
// bit-identical to the validated round-4 chain (d strictly ascending 0..255).
__global__ __launch_bounds__(256, 2)
void argmin_np_kernel(const float* __restrict__ z, const float* __restrict__ emb,
                      const float* __restrict__ a32, const float* __restrict__ c32,
                      float* __restrict__ bvo, int* __restrict__ bio)
{
    __shared__ union {
        struct { float zt[2][BT * 32]; float et[2][BT * 32]; } t;   // 65536 B
        struct { float rb[16][BT]; int ri[16][BT]; } m;             // 16384 B
    } sm;

    const int tid = threadIdx.x;
    const int tx = tid & 15;        // code group: codes 16j+tx
    const int ty = tid >> 4;        // token group: tokens 16i+ty
    const int t0 = blockIdx.x * BT;
    const int k0 = blockIdx.y * KHALF;

    // staging geometry: wave w covers rows {s*32 + 8w .. +7}, lane = lr*8+g
    const int w8 = ((tid >> 6) << 3);       // wave * 8 rows
    const int lr = (tid >> 3) & 7;          // lane row within the 8-row stripe
    const int g4 = ((tid & 7) ^ lr) << 2;   // pre-swizzled source float4 col (floats)
    const float* zsrc = z + (size_t)(t0 + w8 + lr) * D_DIM + g4;
    const float* esrc = emb + (size_t)(w8 + lr) * D_DIM + g4;
    const int ldso = (w8 << 5);             // wave's float offset inside a 4096-float tile

    float a32r[8];
#pragma unroll
    for (int i = 0; i < 8; i++) a32r[i] = a32[t0 + 16 * i + ty];

    float bv[8];
    int bi[8];
#pragma unroll
    for (int i = 0; i < 8; i++) { bv[i] = FLT_MAX; bi[i] = INT_MAX; }

    float acc[8][8];
#pragma unroll
    for (int i = 0; i < 8; i++)
#pragma unroll
        for (int j = 0; j < 8; j++) acc[i][j] = 0.0f;

    // prologue: stage chunk 0 (k-tile 0, d-chunk 0) into buffer 0
#pragma unroll
    for (int s = 0; s < 4; s++) {
        glds16(zsrc + (s << 13), &sm.t.zt[0][ldso + (s << 10)]);
        glds16(esrc + (size_t)k0 * D_DIM + (s << 13), &sm.t.et[0][ldso + (s << 10)]);
    }
    __syncthreads();   // vmcnt drained by barrier: buffer 0 ready

    const int tyx = ty & 7, txx = tx & 7;
    float ckr[8];
    int p = 0;

    for (int ci = 0; ci < NCHUNK; ci++) {
        if ((ci & 7) == 0) {   // prefetch this k-tile's ||e||^2 terms into regs
            const int kb = k0 + ((ci >> 3) << 7);
#pragma unroll
            for (int j = 0; j < 8; j++) ckr[j] = c32[kb + 16 * j + tx];
        }
        if (ci + 1 < NCHUNK) {   // DMA next chunk into the other buffer
            const int cn = ci + 1;
            const int dc = (cn & 7) << 5;
            const size_t ko = (size_t)(k0 + ((cn >> 3) << 7)) * D_DIM;
            float* ztn = sm.t.zt[p ^ 1];
            float* etn = sm.t.et[p ^ 1];
#pragma unroll
            for (int s = 0; s < 4; s++) {
                glds16(zsrc + dc + (s << 13), ztn + ldso + (s << 10));
                glds16(esrc + ko + dc + (s << 13), etn + ldso + (s << 10));
            }
        }
        // compute this chunk: d ascends (q*4 + {x,y,z,w}) within chunk; chunks
        // ascend in d within a k-tile -> exact sequential 0..255 chain per acc.
        const float* zt0 = sm.t.zt[p];
        const float* et0 = sm.t.et[p];
#pragma unroll
        for (int q = 0; q < 8; q++) {
            const float* zb = zt0 + ty * 32 + ((q ^ tyx) << 2);   // read-side unswizzle
            const float* eb = et0 + tx * 32 + ((q ^ txx) << 2);
            float4 av[8], bw[8];
#pragma unroll
            for (int i = 0; i < 8; i++) av[i] = *(const float4*)(zb + (i << 9));
#pragma unroll
            for (int j = 0; j < 8; j++) bw[j] = *(const float4*)(eb + (j << 9));
#pragma unroll
            for (int i = 0; i < 8; i++)
#pragma unroll
                for (int j = 0; j < 8; j++) {
                    acc[i][j] = fmaf(av[i].x, bw[j].x, acc[i][j]);
                    acc[i][j] = fmaf(av[i].y, bw[j].y, acc[i][j]);
                    acc[i][j] = fmaf(av[i].z, bw[j].z, acc[i][j]);
                    acc[i][j] = fmaf(av[i].w, bw[j].w, acc[i][j]);
                }
        }
        if ((ci & 7) == 7) {   // k-tile epilogue: V = fl32(fl32(A-2M)+C), argmin
            const int kb = k0 + ((ci >> 3) << 7);
#pragma unroll
            for (int j = 0; j < 8; j++) {
                const int k = kb + 16 * j + tx;   // per-thread k strictly ascending
#pragma unroll
                for (int i = 0; i < 8; i++) {
                    const float v1 = a32r[i] - 2.0f * acc[i][j];
                    const float v2 = v1 + ckr[j];
                    if (v2 < bv[i]) { bv[i] = v2; bi[i] = k; }
                    acc[i][j] = 0.0f;
                }
            }
        }
        __syncthreads();   // readers of buf p done; DMA into p^1 drained
        p ^= 1;
    }

    // tiles dead; reuse LDS for merge
#pragma unroll
    for (int i = 0; i < 8; i++) {
        sm.m.rb[tx][16 * i + ty] = bv[i];
        sm.m.ri[tx][16 * i + ty] = bi[i];
    }
    __syncthreads();
    if (tid < BT) {
        float B = sm.m.rb[0][tid];
        int I = sm.m.ri[0][tid];
#pragma unroll
        for (int e = 1; e < 16; e++) {
            const float cv = sm.m.rb[e][tid];
            const int ci2 = sm.m.ri[e][tid];
            if (cv < B || (cv == B && ci2 < I)) { B = cv; I = ci2; }
        }
        bvo[(size_t)blockIdx.y * T_TOKENS + t0 + tid] = B;
        bio[(size_t)blockIdx.y * T_TOKENS + t0 + tid] = I;
    }
}

// Merge k-split halves, gather quantized rows, write indices, fp64 loss partials.
__global__ __launch_bounds__(256)
void gather_kernel(const float* __restrict__ z, const float* __restrict__ emb,
                   const float* __restrict__ bvh, const int* __restrict__ bih,
                   float* __restrict__ out, double* __restrict__ partials)
{
    const int tid = threadIdx.x;
    const int base = blockIdx.x * 64;
    __shared__ double lsm[4];
    double lacc = 0.0;
    for (int ti = 0; ti < 64; ti++) {
        const int t = base + ti;
        // numpy first-index: tie -> half 0 (its ks are all smaller)
        const int sel = (bvh[T_TOKENS + t] < bvh[t]) ? bih[T_TOKENS + t] : bih[t];
        const float ev = emb[(size_t)sel * D_DIM + tid];
        const float zv = z[(size_t)t * D_DIM + tid];
        out[(size_t)t * D_DIM + tid] = ev;
        if (tid == 0) out[QOFF + t] = (float)sel;
        const double df = (double)zv - (double)ev;
        lacc += df * df;
    }
    lacc = wave_sum_d(lacc);
    const int lane = tid & 63, w = tid >> 6;
    if (lane == 0) lsm[w] = lacc;
    __syncthreads();
    if (tid == 0) partials[blockIdx.x] = lsm[0] + lsm[1] + lsm[2] + lsm[3];
}

__global__ void finalize_kernel(const double* __restrict__ partials, float* __restrict__ out) {
    __shared__ double rsm[4];
    const int tid = threadIdx.x;
    double s = 0.0;
    for (int i = tid; i < 1024; i += 256) s += partials[i];
    s = wave_sum_d(s);
    if ((tid & 63) == 0) rsm[tid >> 6] = s;
    __syncthreads();
    if (tid == 0) {
        const double mean = (rsm[0] + rsm[1] + rsm[2] + rsm[3]) / (double)QOFF;
        out[QOFF + T_TOKENS] = (float)(1.25 * mean);
    }
}

extern "C" void kernel_launch(void* const* d_in, const int* in_sizes, int n_in,
                              void* d_out, int out_size, void* d_ws, size_t ws_size,
                              hipStream_t stream)
{
    const float* z = (const float*)d_in[0];
    const float* emb = (const float*)d_in[1];
    float* out = (float*)d_out;
    char* ws = (char*)d_ws;

    float* a32 = (float*)ws;                          // 262144 B
    float* c32 = (float*)(ws + 262144);               // 16384 B
    float* bvh = (float*)(ws + 278528);               // 2*65536*4 = 524288 B
    int* bih = (int*)(ws + 802816);                   // 524288 B
    double* partials = (double*)(ws + 1327104);       // 8192 B

    a32_kernel<<<T_TOKENS / 256, 256, 0, stream>>>(z, a32);
    c32_kernel<<<K_EMB, 256, 0, stream>>>(emb, c32);
    argmin_np_kernel<<<dim3(T_TOKENS / BT, 2), 256, 0, stream>>>(z, emb, a32, c32, bvh, bih);
    gather_kernel<<<T_TOKENS / 64, 256, 0, stream>>>(z, emb, bvh, bih, out, partials);
    finalize_kernel<<<1, 256, 0, stream>>>(partials, out);
}

// Round 2
// 2085.302 us; speedup vs baseline: 1.3655x; 1.2128x over previous
//
#include <hip/hip_runtime.h>
#include <cfloat>
#include <climits>

#define T_TOKENS 65536
#define K_EMB 4096
#define D_DIM 256
#define QOFF ((size_t)T_TOKENS * D_DIM)   // 16777216
#define BT 128        // tokens per block
#define KTILE 256     // codes per k-tile (acc[8][16] per thread)
#define KHALF 2048    // codes per k-split half
#define NTILE (KHALF / KTILE)             // 8 k-tiles per half
#define DCH 16        // d-chunk width in floats (64 B rows)
#define NCHUNK (NTILE * (D_DIM / DCH))    // 128 chunks

// fp32 multiply, contraction into later add blocked (numpy rounds the square first)
__device__ __forceinline__ float fmul_nc(float a, float b) {
    float c = a * b;
    asm volatile("" : "+v"(c));
    return c;
}

__device__ __forceinline__ double wave_sum_d(double v) {
#pragma unroll
    for (int o = 32; o >= 1; o >>= 1) v += __shfl_down(v, o, 64);
    return v;
}

// async global->LDS DMA, 16B per lane; lds base must be wave-uniform.
__device__ __forceinline__ void glds16(const float* g, float* l) {
    __builtin_amdgcn_global_load_lds((const __attribute__((address_space(1))) void*)g,
                                     (__attribute__((address_space(3))) void*)l, 16, 0, 0);
}

// A32[t] = np.float32 pairwise sum of z[t]**2 (two 128-halves, 8 strided
// accumulators, ((r0+r1)+(r2+r3))+((r4+r5)+(r6+r7)), then h0+h1). Validated r4.
__global__ __launch_bounds__(256)
void a32_kernel(const float* __restrict__ z, float* __restrict__ a32) {
    __shared__ float lds[64][257];
    const int tid = threadIdx.x;
    const int t0 = blockIdx.x * 256;
    for (int sub = 0; sub < 4; sub++) {
        const int tb = t0 + sub * 64;
        __syncthreads();
        for (int idx = tid; idx < 64 * 256; idx += 256) {
            const int r = idx >> 8, c = idx & 255;
            lds[r][c] = z[(size_t)(tb + r) * D_DIM + c];
        }
        __syncthreads();
        if (tid < 64) {
            const float* row = lds[tid];
            float S[2];
            for (int h = 0; h < 2; h++) {
                const float* p = row + h * 128;
                float r[8];
#pragma unroll
                for (int j = 0; j < 8; j++) r[j] = fmul_nc(p[j], p[j]);
                for (int m = 1; m < 16; m++) {
#pragma unroll
                    for (int j = 0; j < 8; j++) r[j] += fmul_nc(p[8 * m + j], p[8 * m + j]);
                }
                S[h] = ((r[0] + r[1]) + (r[2] + r[3])) + ((r[4] + r[5]) + (r[6] + r[7]));
            }
            a32[tb + tid] = S[0] + S[1];
        }
    }
}

// C32[k] = fp32(||e_k||^2) — the +C add is annihilated by fp32 rounding anyway.
__global__ void c32_kernel(const float* __restrict__ emb, float* __restrict__ c32) {
    const int k = blockIdx.x;
    const double v = (double)emb[(size_t)k * D_DIM + threadIdx.x];
    double s = wave_sum_d(v * v);
    __shared__ double wsm[4];
    const int lane = threadIdx.x & 63, w = threadIdx.x >> 6;
    if (lane == 0) wsm[w] = s;
    __syncthreads();
    if (threadIdx.x == 0) c32[k] = (float)(wsm[0] + wsm[1] + wsm[2] + wsm[3]);
}

// Argmin GEMM, v3: 8x16 register tile (KTILE=256), DCH=16 d-chunks, dbuf LDS
// 48 KB, global_load_lds staging with XOR swizzle: LDS position p of row r
// holds global float4 column p ^ (((r%16)>>1)&3); DMA source pre-swizzled,
// ds_read applies the same involution. Per-(t,k) fp32 fmaf chain remains
// d-ascending 0..255 (bit-identical to validated round-4 chain).
__global__ __launch_bounds__(256, 2)
void argmin_np_kernel(const float* __restrict__ z, const float* __restrict__ emb,
                      const float* __restrict__ a32, const float* __restrict__ c32,
                      float* __restrict__ bvo, int* __restrict__ bio)
{
    __shared__ union {
        struct { float zt[2][BT * DCH]; float et[2][KTILE * DCH]; } t;   // 49152 B
        struct { float rb[16][BT]; int ri[16][BT]; } m;                  // 16384 B
    } sm;

    const int tid = threadIdx.x;
    const int tx = tid & 15;        // code group: codes 16j+tx, j=0..15
    const int ty = tid >> 4;        // token group: tokens 16i+ty, i=0..7
    const int t0 = blockIdx.x * BT;
    const int k0 = blockIdx.y * KHALF;

    // staging geometry: per glds16 a wave covers 16 rows x 64 B.
    const int wv = tid >> 6;               // wave id (0..3)
    const int lrow = (tid >> 2) & 15;      // lane row within 16-row stripe
    const int lslot = tid & 3;             // lane float4 position within row
    const int scol = ((lslot ^ ((lrow >> 1) & 3)) << 2);   // pre-swizzled src col (floats)
    const float* zsrc = z + (size_t)(t0 + wv * 32 + lrow) * D_DIM + scol;
    const float* esrc = emb + (size_t)(wv * 64 + lrow) * D_DIM + scol;
    const int zofs = (wv * 32) * DCH;      // wave-uniform float offsets in LDS tiles
    const int eofs = (wv * 64) * DCH;

    float a32r[8];
#pragma unroll
    for (int i = 0; i < 8; i++) a32r[i] = a32[t0 + 16 * i + ty];

    float bv[8];
    int bi[8];
#pragma unroll
    for (int i = 0; i < 8; i++) { bv[i] = FLT_MAX; bi[i] = INT_MAX; }

    float acc[8][16];
#pragma unroll
    for (int i = 0; i < 8; i++)
#pragma unroll
        for (int j = 0; j < 16; j++) acc[i][j] = 0.0f;

    // prologue: stage chunk 0 (k-tile 0, d-chunk 0) into buffer 0
#pragma unroll
    for (int s = 0; s < 2; s++)
        glds16(zsrc + (s << 12), &sm.t.zt[0][zofs + (s << 8)]);
#pragma unroll
    for (int s = 0; s < 4; s++)
        glds16(esrc + (size_t)k0 * D_DIM + (s << 12), &sm.t.et[0][eofs + (s << 8)]);
    __syncthreads();   // barrier drains vmcnt: buffer 0 ready

    const int tysw = (ty >> 1) & 3;   // read-side swizzle keys
    const int txsw = (tx >> 1) & 3;
    int p = 0;

    for (int ci = 0; ci < NCHUNK; ci++) {
        if (ci + 1 < NCHUNK) {   // DMA next chunk into the other buffer
            const int cn = ci + 1;
            const int dc = (cn & 15) << 4;                       // d offset (floats)
            const size_t ko = (size_t)(k0 + ((cn >> 4) << 8)) * D_DIM + dc;
            float* ztn = sm.t.zt[p ^ 1];
            float* etn = sm.t.et[p ^ 1];
#pragma unroll
            for (int s = 0; s < 2; s++)
                glds16(zsrc + dc + (s << 12), ztn + zofs + (s << 8));
#pragma unroll
            for (int s = 0; s < 4; s++)
                glds16(esrc + ko + (s << 12), etn + eofs + (s << 8));
        }
        // compute this chunk: d ascends (q*4 + {x,y,z,w}); chunks ascend in d
        // within a k-tile -> exact sequential 0..255 chain per acc.
        const float* zt0 = sm.t.zt[p];
        const float* et0 = sm.t.et[p];
        for (int q = 0; q < 4; q++) {
            const float* zb = zt0 + ty * DCH + ((q ^ tysw) << 2);
            const float* eb = et0 + tx * DCH + ((q ^ txsw) << 2);
            float4 av[8];
#pragma unroll
            for (int i = 0; i < 8; i++) av[i] = *(const float4*)(zb + (i << 8));
#pragma unroll
            for (int jh = 0; jh < 2; jh++) {
                float4 bw[8];
#pragma unroll
                for (int jj = 0; jj < 8; jj++)
                    bw[jj] = *(const float4*)(eb + ((jh * 8 + jj) << 8));
#pragma unroll
                for (int i = 0; i < 8; i++)
#pragma unroll
                    for (int jj = 0; jj < 8; jj++) {
                        float* a = &acc[i][jh * 8 + jj];
                        *a = fmaf(av[i].x, bw[jj].x, *a);
                        *a = fmaf(av[i].y, bw[jj].y, *a);
                        *a = fmaf(av[i].z, bw[jj].z, *a);
                        *a = fmaf(av[i].w, bw[jj].w, *a);
                    }
            }
        }
        if ((ci & 15) == 15) {   // k-tile epilogue: V = fl32(fl32(A-2M)+C), argmin
            const int kb = k0 + ((ci >> 4) << 8);
#pragma unroll
            for (int j = 0; j < 16; j++) {
                const int k = kb + 16 * j + tx;   // per-thread k strictly ascending
                const float ck = c32[k];
#pragma unroll
                for (int i = 0; i < 8; i++) {
                    const float v1 = a32r[i] - 2.0f * acc[i][j];
                    const float v2 = v1 + ck;
                    if (v2 < bv[i]) { bv[i] = v2; bi[i] = k; }
                    acc[i][j] = 0.0f;
                }
            }
        }
        __syncthreads();   // readers of buf p done; DMA into p^1 drained
        p ^= 1;
    }

    // tiles dead; reuse LDS for merge
#pragma unroll
    for (int i = 0; i < 8; i++) {
        sm.m.rb[tx][16 * i + ty] = bv[i];
        sm.m.ri[tx][16 * i + ty] = bi[i];
    }
    __syncthreads();
    if (tid < BT) {
        float B = sm.m.rb[0][tid];
        int I = sm.m.ri[0][tid];
#pragma unroll
        for (int e = 1; e < 16; e++) {
            const float cv = sm.m.rb[e][tid];
            const int ci2 = sm.m.ri[e][tid];
            if (cv < B || (cv == B && ci2 < I)) { B = cv; I = ci2; }
        }
        bvo[(size_t)blockIdx.y * T_TOKENS + t0 + tid] = B;
        bio[(size_t)blockIdx.y * T_TOKENS + t0 + tid] = I;
    }
}

// Merge k-split halves, gather quantized rows, write indices, fp64 loss partials.
__global__ __launch_bounds__(256)
void gather_kernel(const float* __restrict__ z, const float* __restrict__ emb,
                   const float* __restrict__ bvh, const int* __restrict__ bih,
                   float* __restrict__ out, double* __restrict__ partials)
{
    const int tid = threadIdx.x;
    const int base = blockIdx.x * 64;
    __shared__ double lsm[4];
    double lacc = 0.0;
    for (int ti = 0; ti < 64; ti++) {
        const int t = base + ti;
        // numpy first-index: tie -> half 0 (its ks are all smaller)
        const int sel = (bvh[T_TOKENS + t] < bvh[t]) ? bih[T_TOKENS + t] : bih[t];
        const float ev = emb[(size_t)sel * D_DIM + tid];
        const float zv = z[(size_t)t * D_DIM + tid];
        out[(size_t)t * D_DIM + tid] = ev;
        if (tid == 0) out[QOFF + t] = (float)sel;
        const double df = (double)zv - (double)ev;
        lacc += df * df;
    }
    lacc = wave_sum_d(lacc);
    const int lane = tid & 63, w = tid >> 6;
    if (lane == 0) lsm[w] = lacc;
    __syncthreads();
    if (tid == 0) partials[blockIdx.x] = lsm[0] + lsm[1] + lsm[2] + lsm[3];
}

__global__ void finalize_kernel(const double* __restrict__ partials, float* __restrict__ out) {
    __shared__ double rsm[4];
    const int tid = threadIdx.x;
    double s = 0.0;
    for (int i = tid; i < 1024; i += 256) s += partials[i];
    s = wave_sum_d(s);
    if ((tid & 63) == 0) rsm[tid >> 6] = s;
    __syncthreads();
    if (tid == 0) {
        const double mean = (rsm[0] + rsm[1] + rsm[2] + rsm[3]) / (double)QOFF;
        out[QOFF + T_TOKENS] = (float)(1.25 * mean);
    }
}

extern "C" void kernel_launch(void* const* d_in, const int* in_sizes, int n_in,
                              void* d_out, int out_size, void* d_ws, size_t ws_size,
                              hipStream_t stream)
{
    const float* z = (const float*)d_in[0];
    const float* emb = (const float*)d_in[1];
    float* out = (float*)d_out;
    char* ws = (char*)d_ws;

    float* a32 = (float*)ws;                          // 262144 B
    float* c32 = (float*)(ws + 262144);               // 16384 B
    float* bvh = (float*)(ws + 278528);               // 2*65536*4 = 524288 B
    int* bih = (int*)(ws + 802816);                   // 524288 B
    double* partials = (double*)(ws + 1327104);       // 8192 B

    a32_kernel<<<T_TOKENS / 256, 256, 0, stream>>>(z, a32);
    c32_kernel<<<K_EMB, 256, 0, stream>>>(emb, c32);
    argmin_np_kernel<<<dim3(T_TOKENS / BT, 2), 256, 0, stream>>>(z, emb, a32, c32, bvh, bih);
    gather_kernel<<<T_TOKENS / 64, 256, 0, stream>>>(z, emb, bvh, bih, out, partials);
    finalize_kernel<<<1, 256, 0, stream>>>(partials, out);
}